// Round 1
// baseline (510.876 us; speedup 1.0000x reference)
//
#include <hip/hip_runtime.h>

// EdgeFeature: out[b,n,k,:] = concat(central(64), neighbor(64), rel(64), ||rel||^2(1))
// B=4 N=8192 C=64 K=20  -> 655360 edges, row = 193 floats, output = 506 MB.
//
// Structure: 16 lanes per edge (4 channels each as f4), 4 edges per wave,
// 4 waves per block. Each wave stages its 4 edges (772 floats = 193 f4,
// 16B-aligned) in a PRIVATE LDS slice and streams it out itself —
// no __syncthreads anywhere (same-wave DS ordering suffices).
// Stores are plain cached f4 (the 6.27 TB/s fill on this box uses plain
// stores; nontemporal is the untested variable being removed).

typedef float f4v __attribute__((ext_vector_type(4)));

#define BLOCK 256

constexpr int Bc = 4, Nc = 8192, Kc = 20;
constexpr int NK = Nc * Kc;                 // 163840
constexpr int TOTAL_EDGES = Bc * NK;        // 655360
constexpr int ROW = 193;                    // 3*64 + 1 floats per edge
constexpr int WPB = BLOCK / 64;             // 4 waves / block
constexpr int EPW = 4;                      // edges / wave
constexpr int EPB = WPB * EPW;              // 16 edges / block
constexpr int WAVE_FLOATS = EPW * ROW;      // 772 (divisible by 4 -> aligned f4)
constexpr int WAVE_F4 = WAVE_FLOATS / 4;    // 193

__global__ __launch_bounds__(BLOCK)
void edge_feature_kernel(const float* __restrict__ pc,
                         const int* __restrict__ nn_idx,
                         float* __restrict__ out)
{
    __shared__ float lds[WPB][WAVE_FLOATS];

    const int tid  = threadIdx.x;
    const int wv   = tid >> 6;        // wave in block
    const int lane = tid & 63;
    const int ew   = lane >> 4;       // edge within wave (0..3)
    const int lg   = lane & 15;       // 4-channel group within edge

    const int e = blockIdx.x * EPB + wv * EPW + ew;   // global edge id

    // decode e -> (b, n); k not needed (nn_idx is flat-indexed by e)
    const int b   = e / NK;           // const divisor -> magic mul
    const int rem = e - b * NK;
    const int n   = rem / Kc;

    const int idx = nn_idx[e];

    const f4v* pc4 = (const f4v*)pc;  // pc rows: 64 floats = 16 f4, 256B aligned
    f4v cen = pc4[(b * Nc + n)   * 16 + lg];
    f4v nbr = pc4[(b * Nc + idx) * 16 + lg];
    f4v rel = nbr - cen;

    float part = rel.x * rel.x + rel.y * rel.y + rel.z * rel.z + rel.w * rel.w;
    // reduce squared distance across the 16 lanes of this edge
    part += __shfl_xor(part, 1, 16);
    part += __shfl_xor(part, 2, 16);
    part += __shfl_xor(part, 4, 16);
    part += __shfl_xor(part, 8, 16);

    // stage into this wave's private LDS slice (2-way bank aliasing only -> free)
    float* row = &lds[wv][ew * ROW];
    const int c0 = lg * 4;
    row[c0 + 0]       = cen.x; row[c0 + 1]       = cen.y;
    row[c0 + 2]       = cen.z; row[c0 + 3]       = cen.w;
    row[64 + c0 + 0]  = nbr.x; row[64 + c0 + 1]  = nbr.y;
    row[64 + c0 + 2]  = nbr.z; row[64 + c0 + 3]  = nbr.w;
    row[128 + c0 + 0] = rel.x; row[128 + c0 + 1] = rel.y;
    row[128 + c0 + 2] = rel.z; row[128 + c0 + 3] = rel.w;
    if (lg == 0) row[192] = part;

    // no barrier: this wave reads only what it wrote (DS pipe is in-order
    // per wave; compiler inserts the lgkmcnt wait).
    const f4v* l4 = (const f4v*)&lds[wv][0];
    f4v* out4 = (f4v*)(out + (size_t)(blockIdx.x * EPB + wv * EPW) * ROW);

    // 193 f4 per wave: 3 full rounds + 1 tail element (lane 0)
    out4[lane]        = l4[lane];
    out4[lane + 64]   = l4[lane + 64];
    out4[lane + 128]  = l4[lane + 128];
    if (lane == 0) out4[192] = l4[192];
}

extern "C" void kernel_launch(void* const* d_in, const int* in_sizes, int n_in,
                              void* d_out, int out_size, void* d_ws, size_t ws_size,
                              hipStream_t stream)
{
    const float* pc     = (const float*)d_in[0];
    const int*   nn_idx = (const int*)d_in[1];
    float*       out    = (float*)d_out;

    const int grid = TOTAL_EDGES / EPB;   // 40960 blocks
    edge_feature_kernel<<<grid, BLOCK, 0, stream>>>(pc, nn_idx, out);
}

// Round 2
// 510.719 us; speedup vs baseline: 1.0003x; 1.0003x over previous
//
#include <hip/hip_runtime.h>

// EdgeFeature: out[b,n,k,:] = concat(central(64), neighbor(64), rel(64), ||rel||^2(1))
// B=4 N=8192 C=64 K=20  -> 655360 edges, row = 193 floats, output = 506 MB.
//
// Structure: 16 lanes per edge (4 channels each as f4), 4 edges per wave,
// 4 waves per block, wave-private LDS slice, no __syncthreads.
//
// R2 change: batch-per-XCD swizzle. xcd = blockIdx%8 (round-robin dispatch
// heuristic); batch = xcd&3, so each XCD's L2 only holds ONE batch's 2 MB
// pc slice (vs all 8 MB before) while the 506 MB write stream flows through.
// Stores are nontemporal (evict-first in L2) to protect the pc slice.

typedef float f4v __attribute__((ext_vector_type(4)));

#define BLOCK 256

constexpr int Bc = 4, Nc = 8192, Kc = 20;
constexpr int NK = Nc * Kc;                   // 163840 edges per batch
constexpr int TOTAL_EDGES = Bc * NK;          // 655360
constexpr int ROW = 193;                      // 3*64 + 1 floats per edge
constexpr int WPB = 4;                        // waves / block
constexpr int EPW = 4;                        // edges / wave
constexpr int EPB = WPB * EPW;                // 16 edges / block
constexpr int WAVE_FLOATS = EPW * ROW;        // 772 (divisible by 4 -> aligned f4)
constexpr int BLOCKS_PER_BATCH = NK / EPB;    // 10240
constexpr int GRID = TOTAL_EDGES / EPB;       // 40960
constexpr int HALF = BLOCKS_PER_BATCH / 2;    // 5120 (each batch spans 2 XCDs)

__global__ __launch_bounds__(BLOCK)
void edge_feature_kernel(const float* __restrict__ pc,
                         const int* __restrict__ nn_idx,
                         float* __restrict__ out)
{
    __shared__ float lds[WPB][WAVE_FLOATS];

    const int tid  = threadIdx.x;
    const int wv   = tid >> 6;        // wave in block
    const int lane = tid & 63;
    const int ew   = lane >> 4;       // edge within wave (0..3)
    const int lg   = lane & 15;       // 4-channel group within edge

    // ---- batch-per-XCD swizzle ----
    // dispatch round-robins blocks over 8 XCDs: xcd = blockIdx % 8.
    // batches 0..3 -> XCD pairs {0,4},{1,5},{2,6},{3,7}.
    const int xcd  = blockIdx.x & 7;
    const int slot = blockIdx.x >> 3;            // 0..5119
    const int b    = xcd & 3;                    // this XCD's batch
    const int wb   = (xcd >> 2) * HALF + slot;   // within-batch block 0..10239

    const int er = wb * EPB + wv * EPW + ew;     // edge within batch
    const int e  = b * NK + er;                  // global (flat) edge id
    const int n  = er / Kc;                      // central row (const divisor)

    const int idx = nn_idx[e];

    const f4v* pc4 = (const f4v*)pc;  // pc rows: 64 floats = 16 f4, 256B aligned
    f4v cen = pc4[(b * Nc + n)   * 16 + lg];
    f4v nbr = pc4[(b * Nc + idx) * 16 + lg];
    f4v rel = nbr - cen;

    float part = rel.x * rel.x + rel.y * rel.y + rel.z * rel.z + rel.w * rel.w;
    // reduce squared distance across the 16 lanes of this edge
    part += __shfl_xor(part, 1, 16);
    part += __shfl_xor(part, 2, 16);
    part += __shfl_xor(part, 4, 16);
    part += __shfl_xor(part, 8, 16);

    // stage into this wave's private LDS slice
    float* row = &lds[wv][ew * ROW];
    const int c0 = lg * 4;
    row[c0 + 0]       = cen.x; row[c0 + 1]       = cen.y;
    row[c0 + 2]       = cen.z; row[c0 + 3]       = cen.w;
    row[64 + c0 + 0]  = nbr.x; row[64 + c0 + 1]  = nbr.y;
    row[64 + c0 + 2]  = nbr.z; row[64 + c0 + 3]  = nbr.w;
    row[128 + c0 + 0] = rel.x; row[128 + c0 + 1] = rel.y;
    row[128 + c0 + 2] = rel.z; row[128 + c0 + 3] = rel.w;
    if (lg == 0) row[192] = part;

    // no barrier: this wave reads only what it wrote (same-wave DS ordering).
    const f4v* l4 = (const f4v*)&lds[wv][0];
    const long long e0 = (long long)b * NK + (long long)wb * EPB + wv * EPW;
    f4v* out4 = (f4v*)(out + (size_t)e0 * ROW);   // e0 multiple of 4 -> 16B aligned

    // 193 f4 per wave: 3 full rounds + 1 tail element (lane 0).
    // nontemporal: mark write lines evict-first so they don't displace pc in L2.
    __builtin_nontemporal_store(l4[lane],       &out4[lane]);
    __builtin_nontemporal_store(l4[lane + 64],  &out4[lane + 64]);
    __builtin_nontemporal_store(l4[lane + 128], &out4[lane + 128]);
    if (lane == 0) __builtin_nontemporal_store(l4[192], &out4[192]);
}

extern "C" void kernel_launch(void* const* d_in, const int* in_sizes, int n_in,
                              void* d_out, int out_size, void* d_ws, size_t ws_size,
                              hipStream_t stream)
{
    const float* pc     = (const float*)d_in[0];
    const int*   nn_idx = (const int*)d_in[1];
    float*       out    = (float*)d_out;

    edge_feature_kernel<<<GRID, BLOCK, 0, stream>>>(pc, nn_idx, out);
}